// Round 10
// baseline (22.770 us; speedup 1.0000x reference)
//
#include <hip/hip_runtime.h>

constexpr int B  = 2;
constexpr int L  = 256;
constexpr int Dd = 512;
constexpr int Hh = 256;
constexpr int Oo = 16;
constexpr int BL = B * L;
constexpr int NBO = B * Oo;          // 32
constexpr int SLAB = NBO * L;        // 8192 floats per partial slot

__device__ __forceinline__ float leaky(const float v) {
    return (v >= 0.f) ? v : 0.1f * v;
}
__device__ __forceinline__ void fma4(float& acc, const float4 a, const float4 b) {
    acc = fmaf(a.x, b.x, acc);
    acc = fmaf(a.y, b.y, acc);
    acc = fmaf(a.z, b.z, acc);
    acc = fmaf(a.w, b.w, acc);
}

// Sum across each row-of-16 lanes using DPP row-rotates (VALU pipe, not DS).
__device__ __forceinline__ float red16(float v) {
    v += __int_as_float(__builtin_amdgcn_update_dpp(
            0, __float_as_int(v), 0x128, 0xF, 0xF, true)); // row_ror:8
    v += __int_as_float(__builtin_amdgcn_update_dpp(
            0, __float_as_int(v), 0x124, 0xF, 0xF, true)); // row_ror:4
    v += __int_as_float(__builtin_amdgcn_update_dpp(
            0, __float_as_int(v), 0x122, 0xF, 0xF, true)); // row_ror:2
    v += __int_as_float(__builtin_amdgcn_update_dpp(
            0, __float_as_int(v), 0x121, 0xF, 0xF, true)); // row_ror:1
    return v;
}

// ---------------------------------------------------------------------------
// K1: fused MLP + partial projection — DS-instruction-halved tile.
// grid = (64 rowsets of 8, 4 h-chunks of 64, 2 matrices) = 512 blocks,
// block = 128 thr (2 waves). Lane (kl,g) owns 8 W rows (wave covers 32 h,
// block covers 64 h — same slice as R9). Per k-step a lane does 8 ds_read
// (one per row) reused across 8 h = 32 FMA per ds_read (2x R9) -> per-CU DS
// 6.1k -> ~3.4k cy; VALU wall unchanged. W-from-L2 stays 64 MB (R7 lesson);
// rows/block stays 8 (R8 lesson). k-reduction via DPP (VALU).
// Phase B byte-identical to R9 (block = exactly the 128 threads that ran it).
// ---------------------------------------------------------------------------
__global__ __launch_bounds__(128, 2) void mlp_proj_kernel(
    const float* __restrict__ x,
    const float* __restrict__ W1, const float* __restrict__ b1,
    const float* __restrict__ W2, const float* __restrict__ b2,
    const float* __restrict__ Wf,
    float* __restrict__ PA, float* __restrict__ PB, float* __restrict__ PD)
{
    const int rs = blockIdx.x;   // rowset: 8 bl-rows
    const int hc = blockIdx.y;   // h-chunk: 64 h
    const int m  = blockIdx.z;
    const float* __restrict__ W  = m ? W2 : W1;
    const float* __restrict__ bb = m ? b2 : b1;

    __shared__ float xs[8 * Dd];       // 16 KB
    __shared__ float hbuf[8][64];      // 2 KB
    const int t = threadIdx.x;         // 0..127
    {
        const float4* xg = reinterpret_cast<const float4*>(x + (size_t)rs * 8 * Dd);
        float4* s4 = reinterpret_cast<float4*>(xs);
        #pragma unroll
        for (int i = 0; i < 8; ++i) s4[t + 128 * i] = xg[t + 128 * i];
    }
    __syncthreads();

    const int wave = t >> 6, lane = t & 63, g = lane >> 4, kl = lane & 15;
    const int h0 = hc * 64 + wave * 32 + g * 8;   // first of this lane's 8 h

    const float4* wp[8];
    #pragma unroll
    for (int j = 0; j < 8; ++j)
        wp[j] = reinterpret_cast<const float4*>(W + (size_t)(h0 + j) * Dd);
    const float4* xs4 = reinterpret_cast<const float4*>(xs);

    float acc[8][8];
    #pragma unroll
    for (int r = 0; r < 8; ++r)
        #pragma unroll
        for (int j = 0; j < 8; ++j) acc[r][j] = 0.f;

    #pragma unroll
    for (int s = 0; s < 8; ++s) {
        const int ko = s * 16 + kl;
        float4 wv[8];
        #pragma unroll
        for (int j = 0; j < 8; ++j) wv[j] = wp[j][ko];
        #pragma unroll
        for (int r = 0; r < 8; ++r) {
            const float4 xv = xs4[r * 128 + ko];
            #pragma unroll
            for (int j = 0; j < 8; ++j)
                fma4(acc[r][j], xv, wv[j]);
        }
    }

    #pragma unroll
    for (int r = 0; r < 8; ++r)
        #pragma unroll
        for (int j = 0; j < 8; ++j)
            acc[r][j] = red16(acc[r][j]);

    if (kl == 0) {
        const int hl = wave * 32 + g * 8;   // block-local h base
        float bv[8];
        #pragma unroll
        for (int j = 0; j < 8; ++j) bv[j] = bb[h0 + j];
        #pragma unroll
        for (int r = 0; r < 8; ++r) {
            float4 o0, o1;
            o0.x = leaky(acc[r][0] + bv[0]);
            o0.y = leaky(acc[r][1] + bv[1]);
            o0.z = leaky(acc[r][2] + bv[2]);
            o0.w = leaky(acc[r][3] + bv[3]);
            o1.x = leaky(acc[r][4] + bv[4]);
            o1.y = leaky(acc[r][5] + bv[5]);
            o1.z = leaky(acc[r][6] + bv[6]);
            o1.w = leaky(acc[r][7] + bv[7]);
            *reinterpret_cast<float4*>(&hbuf[r][hl])     = o0;
            *reinterpret_cast<float4*>(&hbuf[r][hl + 4]) = o1;
        }
    }
    __syncthreads();

    // Phase B: partial projections over the 64-h slice (all 128 threads).
    {
        const int r = t >> 4, o = t & 15;
        const float4* wf1 = reinterpret_cast<const float4*>(Wf + (size_t)o * (3 * Hh) + hc * 64);
        const float4* wf2 = reinterpret_cast<const float4*>(Wf + (size_t)o * (3 * Hh) + Hh + hc * 64);
        const float4* wf3 = reinterpret_cast<const float4*>(Wf + (size_t)o * (3 * Hh) + 2 * Hh + hc * 64);
        const float4* hv  = reinterpret_cast<const float4*>(&hbuf[r][0]);

        float s1 = 0.f, s2 = 0.f, s3 = 0.f;
        #pragma unroll
        for (int k = 0; k < 16; ++k) {
            const float4 h4 = hv[k];
            fma4(s1, wf1[k], h4);
            fma4(s2, wf2[k], h4);
            if (m == 0) fma4(s3, wf3[k], h4);
        }

        const int bl = rs * 8 + r;
        const int b = bl >> 8, l = bl & 255;
        const size_t idx = ((size_t)(b * Oo + o)) * L + l;
        if (m == 0) {
            PA[(size_t)hc * SLAB + idx] = s1;
            PB[(size_t)hc * SLAB + idx] = 0.5f * s2;
            PD[(size_t)hc * SLAB + idx] = s3;
        } else {
            PA[(size_t)(4 + hc) * SLAB + idx] = 0.5f * s2;
            PB[(size_t)(4 + hc) * SLAB + idx] = -s1;
        }
    }
}

// ---------------------------------------------------------------------------
// K2: partial-reduce + cumsum + epilogue (byte-identical to R4/R9).
// grid = 32 bo x 16 i-chunks = 512 blocks, 256 thr.
//   out[bo,i,j] = A[j] + Bv[i] + bf[o] + (C[j]-C[i-1])/(j-i+1+1e-9)
// i = j+1 numerator exactly 0 (identical LDS values) -> no 1e9 blowup.
// ---------------------------------------------------------------------------
__global__ __launch_bounds__(256) void out_kernel(
    const float* __restrict__ PA, const float* __restrict__ PB,
    const float* __restrict__ PD, const float* __restrict__ bf,
    float* __restrict__ out)
{
    const int bo = blockIdx.x >> 4;    // 0..31
    const int ig = blockIdx.x & 15;    // i-chunk of 16
    const int t  = threadIdx.x;

    __shared__ float Asm[L], Bsm[L], ca[L], cb[L];
    {
        float a = 0.f, bsum = 0.f, d = 0.f;
        #pragma unroll
        for (int s = 0; s < 8; ++s) {
            a    += PA[(size_t)s * SLAB + (size_t)bo * L + t];
            bsum += PB[(size_t)s * SLAB + (size_t)bo * L + t];
        }
        #pragma unroll
        for (int s = 0; s < 4; ++s)
            d += PD[(size_t)s * SLAB + (size_t)bo * L + t];
        Asm[t] = a; Bsm[t] = bsum; ca[t] = d;
    }
    __syncthreads();

    float* src = ca;
    float* dst = cb;
    #pragma unroll
    for (int off = 1; off < L; off <<= 1) {
        const float s = src[t] + ((t >= off) ? src[t - off] : 0.f);
        dst[t] = s;
        __syncthreads();
        float* tmp = src; src = dst; dst = tmp;
    }
    // src[l] = inclusive prefix C[l]

    const float bfv = bf[bo & (Oo - 1)];
    const int j0 = (t & 63) * 4;
    const int is = t >> 6;

    const float4 Av = *reinterpret_cast<const float4*>(Asm + j0);
    const float4 Cv = *reinterpret_cast<const float4*>(src + j0);

    #pragma unroll
    for (int ii = 0; ii < 4; ++ii) {
        const int i = ig * 16 + is * 4 + ii;
        const float cp   = (i > 0) ? src[i - 1] : 0.f;
        const float base = Bsm[i] + bfv;
        float4 r;
        r.x = Av.x + base + (Cv.x - cp) / ((float)(j0 + 0 - i + 1) + 1e-9f);
        r.y = Av.y + base + (Cv.y - cp) / ((float)(j0 + 1 - i + 1) + 1e-9f);
        r.z = Av.z + base + (Cv.z - cp) / ((float)(j0 + 2 - i + 1) + 1e-9f);
        r.w = Av.w + base + (Cv.w - cp) / ((float)(j0 + 3 - i + 1) + 1e-9f);
        *reinterpret_cast<float4*>(out + ((size_t)bo * L + i) * L + j0) = r;
    }
}

// ---------------------------------------------------------------------------
extern "C" void kernel_launch(void* const* d_in, const int* in_sizes, int n_in,
                              void* d_out, int out_size, void* d_ws, size_t ws_size,
                              hipStream_t stream)
{
    const float* x  = (const float*)d_in[0];
    const float* W1 = (const float*)d_in[1];
    const float* b1 = (const float*)d_in[2];
    const float* W2 = (const float*)d_in[3];
    const float* b2 = (const float*)d_in[4];
    const float* Wf = (const float*)d_in[5];
    const float* bf = (const float*)d_in[6];
    float* out = (float*)d_out;

    float* ws = (float*)d_ws;
    float* PA = ws;                       // 8 * SLAB
    float* PB = PA + 8 * (size_t)SLAB;    // 8 * SLAB
    float* PD = PB + 8 * (size_t)SLAB;    // 4 * SLAB

    hipLaunchKernelGGL(mlp_proj_kernel, dim3(BL / 8, 4, 2), dim3(128), 0, stream,
                       x, W1, b1, W2, b2, Wf, PA, PB, PD);
    hipLaunchKernelGGL(out_kernel, dim3(NBO * 16), dim3(256), 0, stream,
                       PA, PB, PD, bf, out);
}